// Round 2
// baseline (33139.969 us; speedup 1.0000x reference)
//
#include <hip/hip_runtime.h>
#include <math.h>

#define BATCH 128
#define SEQ 512
#define HID 512
#define NGROUP 8              // batch groups of 16; group g = bid & 7
#define GB 16                 // batches per group
#define BPG 32                // blocks per group (each owns 16 n-cols)
#define NPB 16                // n-cols per block
#define HT (HID*BATCH)        // one H_T slot: [n][b] transposed, 65536 floats
// ws layout (floats): [0, 2*HT) H_T ping-pong | then flags (8 groups * 64 ints)

__global__ void lstm_init(const float* __restrict__ H0, float* __restrict__ ws) {
    int idx = blockIdx.x * blockDim.x + threadIdx.x;
    if (idx < HT) {
        int n = idx >> 7, b = idx & 127;
        ws[idx] = H0[b * HID + n];          // slot0 = H_T(t=0)
    } else if (idx < HT + NGROUP * 64) {
        ((int*)(ws + 2 * HT))[idx - HT] = 0; // flags = 0 (ws is re-poisoned each call)
    }
}

__global__ __launch_bounds__(256, 1)
void lstm_main(const float* __restrict__ x,
               const float* __restrict__ C0,
               const float* __restrict__ Wi, const float* __restrict__ bi,
               const float* __restrict__ Wf, const float* __restrict__ bf_,
               const float* __restrict__ Wc, const float* __restrict__ bc,
               const float* __restrict__ Wo, const float* __restrict__ bo,
               float* __restrict__ out, float* __restrict__ ws) {
    float* hbuf = ws;
    int* flags  = (int*)(ws + 2 * HT);

    const int bid = blockIdx.x;
    const int g   = bid & 7;            // group (bid%8 -> round-robin XCD heuristic)
    const int cb  = bid >> 3;           // 0..31: which 16-col slice this block owns
    const int tid = threadIdx.x;

    // compute-phase decode: tid = n*16 + g2*8 + kq
    const int n   = tid >> 4;           // 0..15 local n-col
    const int g2  = (tid >> 3) & 1;     // gate pair: 0 -> {I,F}, 1 -> {C,O}
    const int kq  = tid & 7;            // k-octant: k in [kq*64, kq*64+64)
    const int ng  = cb * NPB + n;       // global n for weights

    // epilogue decode: one (n,b) output per thread
    const int ne  = tid >> 4;           // epilogue n  (0..15)
    const int be  = tid & 15;           // epilogue b  (0..15)
    const int neg = cb * NPB + ne;      // global n
    const int bg  = g * GB + be;        // global b

    // ---- weights -> registers (immune to per-step cache invalidation) ----
    const float* WA = g2 ? Wc : Wi;
    const float* WB = g2 ? Wo : Wf;
    float wA[64], wB[64];
    #pragma unroll
    for (int kk = 0; kk < 64; ++kk) {
        int row = (kq * 64 + kk + 1) * HID + ng;   // rows 1..512 are H weights
        wA[kk] = WA[row];
        wB[kk] = WB[row];
    }

    // per-thread epilogue constants (row 0 = x weight, bias) + C state
    const float biasI = bi[neg], biasF = bf_[neg], biasC = bc[neg], biasO = bo[neg];
    const float w0I = Wi[neg], w0F = Wf[neg], w0C = Wc[neg], w0O = Wo[neg];
    float Cst = C0[bg * HID + neg];
    const float* xrow = x + bg * SEQ;

    __shared__ float part[NPB * 4 * GB];   // [n][gate][b] pre-activation partials, 4 KB

    int* myflag = flags + g * 64 + cb;

    for (int t = 0; t < SEQ; ++t) {
        float xv = xrow[t];   // prefetch before the flag wait

        // ---- wait for H_t from all 32 blocks of this group ----
        if (tid < BPG) {
            const int* fp = flags + g * 64 + tid;
            while (__hip_atomic_load(fp, __ATOMIC_RELAXED, __HIP_MEMORY_SCOPE_AGENT) < t) { }
        }
        __syncthreads();
        __threadfence();      // acquire: drop stale L1/L2 before reading H_t

        // ---- partial dot products: 2 gates x 16 b x 64 k per thread ----
        float accA[GB], accB[GB];
        #pragma unroll
        for (int b = 0; b < GB; ++b) { accA[b] = 0.f; accB[b] = 0.f; }

        const float* hp = hbuf + (t & 1) * HT + (kq * 64) * BATCH + g * GB;
        #pragma unroll
        for (int kk = 0; kk < 64; ++kk) {
            const float* hrow = hp + kk * BATCH;
            float h[GB];
            *(float4*)(h + 0)  = *(const float4*)(hrow + 0);
            *(float4*)(h + 4)  = *(const float4*)(hrow + 4);
            *(float4*)(h + 8)  = *(const float4*)(hrow + 8);
            *(float4*)(h + 12) = *(const float4*)(hrow + 12);
            float wa = wA[kk], wb = wB[kk];
            #pragma unroll
            for (int b = 0; b < GB; ++b) {
                accA[b] = fmaf(h[b], wa, accA[b]);
                accB[b] = fmaf(h[b], wb, accB[b]);
            }
        }

        // ---- reduce across the 8 kq lanes (in-wave butterfly, masks 1,2,4) ----
        #pragma unroll
        for (int m = 1; m < 8; m <<= 1) {
            #pragma unroll
            for (int b = 0; b < GB; ++b) {
                accA[b] += __shfl_xor(accA[b], m, 64);
                accB[b] += __shfl_xor(accB[b], m, 64);
            }
        }
        if (kq == 0) {
            #pragma unroll
            for (int b = 0; b < GB; ++b) {
                part[(n * 4 + g2 * 2 + 0) * GB + b] = accA[b];
                part[(n * 4 + g2 * 2 + 1) * GB + b] = accB[b];
            }
        }
        __syncthreads();

        // ---- epilogue: one (n,b) output per thread ----
        float aI = fmaf(xv, w0I, biasI) + part[(ne * 4 + 0) * GB + be];
        float aF = fmaf(xv, w0F, biasF) + part[(ne * 4 + 1) * GB + be];
        float aC = fmaf(xv, w0C, biasC) + part[(ne * 4 + 2) * GB + be];
        float aO = fmaf(xv, w0O, biasO) + part[(ne * 4 + 3) * GB + be];
        float I  = 1.0f / (1.0f + expf(-aI));
        float F  = 1.0f / (1.0f + expf(-aF));
        float Ch = tanhf(aC);
        Cst = fmaf(F, Cst, I * Ch);
        float Hn = aO * tanhf(Cst);        // reference: O has NO sigmoid

        if (t < SEQ - 1) {
            hbuf[((t + 1) & 1) * HT + neg * BATCH + bg] = Hn;
        } else {
            int o = bg * HID + neg;
            out[o] = Hn; out[HT + o] = Hn; out[2 * HT + o] = Cst;
        }

        __syncthreads();                   // all stores issued
        if (tid == 0) {
            __threadfence();               // release H_{t+1}
            __hip_atomic_store(myflag, t + 1, __ATOMIC_RELEASE, __HIP_MEMORY_SCOPE_AGENT);
        }
    }
}

extern "C" void kernel_launch(void* const* d_in, const int* in_sizes, int n_in,
                              void* d_out, int out_size, void* d_ws, size_t ws_size,
                              hipStream_t stream) {
    const float* x  = (const float*)d_in[0];
    const float* H0 = (const float*)d_in[1];
    const float* C0 = (const float*)d_in[2];
    const float* Wi = (const float*)d_in[3];
    const float* bi = (const float*)d_in[4];
    const float* Wf = (const float*)d_in[5];
    const float* bf = (const float*)d_in[6];
    const float* Wc = (const float*)d_in[7];
    const float* bc = (const float*)d_in[8];
    const float* Wo = (const float*)d_in[9];
    const float* bo = (const float*)d_in[10];
    float* out = (float*)d_out;
    float* ws  = (float*)d_ws;   // needs 2*256KB H_T + 2KB flags = ~514 KB

    const int init_elems = HT + NGROUP * 64;
    hipLaunchKernelGGL(lstm_init, dim3((init_elems + 255) / 256), dim3(256), 0, stream,
                       H0, ws);
    hipLaunchKernelGGL(lstm_main, dim3(NGROUP * BPG), dim3(256), 0, stream,
                       x, C0, Wi, bi, Wf, bf, Wc, bc, Wo, bo, out, ws);
}

// Round 3
// 10169.549 us; speedup vs baseline: 3.2587x; 3.2587x over previous
//
#include <hip/hip_runtime.h>
#include <math.h>

#define BATCH 128
#define SEQ 512
#define HID 512
#define NGROUP 8              // batch groups of 16; group g = bid & 7 (round-robin XCD)
#define GB 16                 // batches per group
#define BPG 32                // blocks per group (each owns 16 n-cols)
#define NPB 16                // n-cols per block
#define HT (HID*BATCH)        // one H_T slot: [n][b] transposed, 65536 floats
// ws layout (floats): [0, 2*HT) H_T ping-pong | flags: 8 groups * 64 ints

// LDS layout for staged H slice (512 rows x 16 batch floats):
// off(r,b) = (r>>6)*1284 + (r&63)*20 + b   (20-word padded rows, 4-word chunk pad)
// -> compute-phase ds_read_b128 across the 8 kq lanes covers all 32 banks: conflict-free.
#define ROWW 20
#define CHUNKW 1284           // 64*20 + 4

__global__ void lstm_init(const float* __restrict__ H0, float* __restrict__ ws) {
    int idx = blockIdx.x * blockDim.x + threadIdx.x;
    if (idx < HT) {
        int n = idx >> 7, b = idx & 127;
        ws[idx] = H0[b * HID + n];            // slot0 = H_T(t=0)
    } else if (idx < HT + NGROUP * 64) {
        ((int*)(ws + 2 * HT))[idx - HT] = 0;  // flags = 0 (ws re-poisoned each call)
    }
}

__global__ __launch_bounds__(256, 1)
void lstm_main(const float* __restrict__ x,
               const float* __restrict__ C0,
               const float* __restrict__ Wi, const float* __restrict__ bi,
               const float* __restrict__ Wf, const float* __restrict__ bf_,
               const float* __restrict__ Wc, const float* __restrict__ bc,
               const float* __restrict__ Wo, const float* __restrict__ bo,
               float* __restrict__ out, float* __restrict__ ws) {
    float* hbuf = ws;
    int* flags  = (int*)(ws + 2 * HT);

    const int bid = blockIdx.x;
    const int g   = bid & 7;
    const int cb  = bid >> 3;
    const int tid = threadIdx.x;

    // compute-phase decode: tid = n*16 + g2*8 + kq
    const int n   = tid >> 4;
    const int g2  = (tid >> 3) & 1;     // 0 -> {I,F}, 1 -> {C,O}
    const int kq  = tid & 7;            // k-octant
    const int ng  = cb * NPB + n;

    // epilogue decode: one (n,b) per thread
    const int ne  = tid >> 4;
    const int be  = tid & 15;
    const int neg = cb * NPB + ne;
    const int bg  = g * GB + be;

    // ---- weights -> registers ----
    const float* WA = g2 ? Wc : Wi;
    const float* WB = g2 ? Wo : Wf;
    float wA[64], wB[64];
    #pragma unroll
    for (int kk = 0; kk < 64; ++kk) {
        int row = (kq * 64 + kk + 1) * HID + ng;
        wA[kk] = WA[row];
        wB[kk] = WB[row];
    }

    const float biasI = bi[neg], biasF = bf_[neg], biasC = bc[neg], biasO = bo[neg];
    const float w0I = Wi[neg], w0F = Wf[neg], w0C = Wc[neg], w0O = Wo[neg];
    float Cst = C0[bg * HID + neg];
    const float* xrow = x + bg * SEQ;

    __shared__ float hlds[8 * CHUNKW];     // 41088 B staged H slice
    __shared__ float part[NPB * 4 * GB];   // 4 KB pre-activation partials

    int* myflag = flags + g * 64 + cb;

    for (int t = 0; t < SEQ; ++t) {
        float xv = xrow[t];                // L1-cached (no fences to evict it)

        // ---- wait for H_t flags (coherent-point loads, no fences) ----
        if (tid < BPG) {
            const int* fp = flags + g * 64 + tid;
            while (__hip_atomic_load(fp, __ATOMIC_RELAXED, __HIP_MEMORY_SCOPE_AGENT) < t) { }
        }
        __syncthreads();

        // ---- stage H_t slice (512 rows x 16 b) into LDS via sc1 atomic loads ----
        const float* hsrc = hbuf + (t & 1) * HT + g * GB;
        #pragma unroll
        for (int rr = 0; rr < 2; ++rr) {
            int r = tid + rr * 256;
            const unsigned long long* src =
                (const unsigned long long*)(hsrc + (size_t)r * BATCH);
            unsigned long long v0 = __hip_atomic_load(src + 0, __ATOMIC_RELAXED, __HIP_MEMORY_SCOPE_AGENT);
            unsigned long long v1 = __hip_atomic_load(src + 1, __ATOMIC_RELAXED, __HIP_MEMORY_SCOPE_AGENT);
            unsigned long long v2 = __hip_atomic_load(src + 2, __ATOMIC_RELAXED, __HIP_MEMORY_SCOPE_AGENT);
            unsigned long long v3 = __hip_atomic_load(src + 3, __ATOMIC_RELAXED, __HIP_MEMORY_SCOPE_AGENT);
            unsigned long long v4 = __hip_atomic_load(src + 4, __ATOMIC_RELAXED, __HIP_MEMORY_SCOPE_AGENT);
            unsigned long long v5 = __hip_atomic_load(src + 5, __ATOMIC_RELAXED, __HIP_MEMORY_SCOPE_AGENT);
            unsigned long long v6 = __hip_atomic_load(src + 6, __ATOMIC_RELAXED, __HIP_MEMORY_SCOPE_AGENT);
            unsigned long long v7 = __hip_atomic_load(src + 7, __ATOMIC_RELAXED, __HIP_MEMORY_SCOPE_AGENT);
            int off = (r >> 6) * CHUNKW + (r & 63) * ROWW;
            float2 f0 = __builtin_bit_cast(float2, v0);
            float2 f1 = __builtin_bit_cast(float2, v1);
            float2 f2 = __builtin_bit_cast(float2, v2);
            float2 f3 = __builtin_bit_cast(float2, v3);
            float2 f4 = __builtin_bit_cast(float2, v4);
            float2 f5 = __builtin_bit_cast(float2, v5);
            float2 f6 = __builtin_bit_cast(float2, v6);
            float2 f7 = __builtin_bit_cast(float2, v7);
            *(float4*)&hlds[off + 0]  = make_float4(f0.x, f0.y, f1.x, f1.y);
            *(float4*)&hlds[off + 4]  = make_float4(f2.x, f2.y, f3.x, f3.y);
            *(float4*)&hlds[off + 8]  = make_float4(f4.x, f4.y, f5.x, f5.y);
            *(float4*)&hlds[off + 12] = make_float4(f6.x, f6.y, f7.x, f7.y);
        }
        __syncthreads();

        // ---- partial dots: 2 gates x 16 b x 64 k per thread, from LDS ----
        float accA[GB], accB[GB];
        #pragma unroll
        for (int b = 0; b < GB; ++b) { accA[b] = 0.f; accB[b] = 0.f; }

        const int cbase = kq * CHUNKW;
        #pragma unroll 8
        for (int kk = 0; kk < 64; ++kk) {
            const float* hr = &hlds[cbase + kk * ROWW];
            float h[GB];
            *(float4*)(h + 0)  = *(const float4*)(hr + 0);
            *(float4*)(h + 4)  = *(const float4*)(hr + 4);
            *(float4*)(h + 8)  = *(const float4*)(hr + 8);
            *(float4*)(h + 12) = *(const float4*)(hr + 12);
            float wa = wA[kk], wb = wB[kk];
            #pragma unroll
            for (int b = 0; b < GB; ++b) {
                accA[b] = fmaf(h[b], wa, accA[b]);
                accB[b] = fmaf(h[b], wb, accB[b]);
            }
        }

        // ---- reduce across 8 kq lanes ----
        #pragma unroll
        for (int m = 1; m < 8; m <<= 1) {
            #pragma unroll
            for (int b = 0; b < GB; ++b) {
                accA[b] += __shfl_xor(accA[b], m, 64);
                accB[b] += __shfl_xor(accB[b], m, 64);
            }
        }
        if (kq == 0) {
            #pragma unroll
            for (int b = 0; b < GB; ++b) {
                part[(n * 4 + g2 * 2 + 0) * GB + b] = accA[b];
                part[(n * 4 + g2 * 2 + 1) * GB + b] = accB[b];
            }
        }
        __syncthreads();

        // ---- epilogue ----
        float aI = fmaf(xv, w0I, biasI) + part[(ne * 4 + 0) * GB + be];
        float aF = fmaf(xv, w0F, biasF) + part[(ne * 4 + 1) * GB + be];
        float aC = fmaf(xv, w0C, biasC) + part[(ne * 4 + 2) * GB + be];
        float aO = fmaf(xv, w0O, biasO) + part[(ne * 4 + 3) * GB + be];
        float I  = 1.0f / (1.0f + expf(-aI));
        float F  = 1.0f / (1.0f + expf(-aF));
        float Ch = tanhf(aC);
        Cst = fmaf(F, Cst, I * Ch);
        float Hn = aO * tanhf(Cst);        // reference: O has NO sigmoid

        if (t < SEQ - 1) {
            // sc1 store -> lands at coherent point; no fence needed
            __hip_atomic_store(&hbuf[((t + 1) & 1) * HT + neg * BATCH + bg], Hn,
                               __ATOMIC_RELAXED, __HIP_MEMORY_SCOPE_AGENT);
            __syncthreads();               // drains vmcnt(0): stores acked at coherent point
            if (tid == 0) {
                __hip_atomic_store(myflag, t + 1, __ATOMIC_RELAXED, __HIP_MEMORY_SCOPE_AGENT);
            }
        } else {
            int o = bg * HID + neg;
            out[o] = Hn; out[HT + o] = Hn; out[2 * HT + o] = Cst;
        }
    }
}

extern "C" void kernel_launch(void* const* d_in, const int* in_sizes, int n_in,
                              void* d_out, int out_size, void* d_ws, size_t ws_size,
                              hipStream_t stream) {
    const float* x  = (const float*)d_in[0];
    const float* H0 = (const float*)d_in[1];
    const float* C0 = (const float*)d_in[2];
    const float* Wi = (const float*)d_in[3];
    const float* bi = (const float*)d_in[4];
    const float* Wf = (const float*)d_in[5];
    const float* bf = (const float*)d_in[6];
    const float* Wc = (const float*)d_in[7];
    const float* bc = (const float*)d_in[8];
    const float* Wo = (const float*)d_in[9];
    const float* bo = (const float*)d_in[10];
    float* out = (float*)d_out;
    float* ws  = (float*)d_ws;   // 2*256KB H_T + 2KB flags

    const int init_elems = HT + NGROUP * 64;
    hipLaunchKernelGGL(lstm_init, dim3((init_elems + 255) / 256), dim3(256), 0, stream,
                       H0, ws);
    hipLaunchKernelGGL(lstm_main, dim3(NGROUP * BPG), dim3(256), 0, stream,
                       x, C0, Wi, bi, Wf, bf, Wc, bc, Wo, bo, out, ws);
}

// Round 5
// 7269.450 us; speedup vs baseline: 4.5588x; 1.3989x over previous
//
#include <hip/hip_runtime.h>
#include <math.h>

#define BATCH 128
#define SEQ 512
#define HID 512
#define NGROUP 8              // batch groups of 16; group g = bid & 7
#define GB 16                 // batches per group
#define BPG 32                // blocks per group (each owns 16 n-cols)
#define NPB 16                // n-cols per block
#define GSTRIDE (HID*GB)      // 8192 floats per group per slot
#define HT (NGROUP*GSTRIDE)   // one slot = 65536 floats (256 KB)
// ws layout (floats): [0, 2*HT) H ping-pong (group-major [g][k][b16]) | flags: 8*64 ints

// LDS layout for staged H slice (512 rows x 16 batch floats):
// off(r,b) = (r>>6)*1284 + (r&63)*20 + b
// -> compute-phase b128 reads: 8 kq-octants start at banks 0,4,...,28 => conflict-free.
#define ROWW 20
#define CHUNKW 1284           // 64*20 + 4

__global__ void lstm_init(const float* __restrict__ H0, float* __restrict__ ws) {
    int idx = blockIdx.x * blockDim.x + threadIdx.x;
    if (idx < HT) {
        int b = idx & 15;
        int k = (idx >> 4) & 511;
        int g = idx >> 13;
        ws[idx] = H0[(g * GB + b) * HID + k];   // slot0 = H(t=0), group-major
    } else if (idx < HT + NGROUP * 64) {
        ((int*)(ws + 2 * HT))[idx - HT] = 0;    // flags = 0
    }
}

__global__ __launch_bounds__(256, 1)
void lstm_main(const float* __restrict__ x,
               const float* __restrict__ C0,
               const float* __restrict__ Wi, const float* __restrict__ bi,
               const float* __restrict__ Wf, const float* __restrict__ bf_,
               const float* __restrict__ Wc, const float* __restrict__ bc,
               const float* __restrict__ Wo, const float* __restrict__ bo,
               float* __restrict__ out, float* __restrict__ ws) {
    float* hbuf = ws;
    int* flags  = (int*)(ws + 2 * HT);

    const int bid = blockIdx.x;
    const int g   = bid & 7;
    const int cb  = bid >> 3;
    const int tid = threadIdx.x;

    // compute-phase decode: tid = n*16 + g2*8 + kq
    const int n   = tid >> 4;
    const int g2  = (tid >> 3) & 1;     // 0 -> {I,F}, 1 -> {C,O}
    const int kq  = tid & 7;            // k-octant
    const int ng  = cb * NPB + n;

    // epilogue decode: one (n,b) per thread
    const int ne  = tid >> 4;
    const int be  = tid & 15;
    const int neg = cb * NPB + ne;
    const int bg  = g * GB + be;

    // ---- weights -> registers (FULL unroll so arrays stay in VGPRs) ----
    const float* WA = g2 ? Wc : Wi;
    const float* WB = g2 ? Wo : Wf;
    float wA[64], wB[64];
    #pragma unroll
    for (int kk = 0; kk < 64; ++kk) {
        int row = (kq * 64 + kk + 1) * HID + ng;
        wA[kk] = WA[row];
        wB[kk] = WB[row];
    }

    const float biasI = bi[neg], biasF = bf_[neg], biasC = bc[neg], biasO = bo[neg];
    const float w0I = Wi[neg], w0F = Wf[neg], w0C = Wc[neg], w0O = Wo[neg];
    float Cst = C0[bg * HID + neg];
    const float* xrow = x + bg * SEQ;

    __shared__ float hlds[8 * CHUNKW];     // 41088 B staged H slice
    __shared__ float part[NPB * 4 * GB];   // 4 KB pre-activation partials

    int* myflag = flags + g * 64 + cb;
    const float* gslice = hbuf + g * GSTRIDE;   // this group's contiguous 32 KB (per slot)

    for (int t = 0; t < SEQ; ++t) {
        float xv = xrow[t];                // plain cached load (read-only input)

        // ---- wait for all 32 producer flags of this group ----
        if (tid < BPG) {
            const int* fp = flags + g * 64 + tid;
            while (__hip_atomic_load(fp, __ATOMIC_RELAXED, __HIP_MEMORY_SCOPE_AGENT) < t) { }
        }
        __syncthreads();

        // ---- stage H_t slice: 32 KB contiguous, coalesced coherent dwordx4 loads ----
        // thread tid reads 128 B at gslice + slot + tid*32 floats (rows 2*tid, 2*tid+1).
        // "=&v" early-clobber: outputs must NOT overlap the address pair %8 (R4 crash).
        {
            const float4* src = (const float4*)(gslice + (t & 1) * HT) + tid * 8;
            float4 v0, v1, v2, v3, v4, v5, v6, v7;
            asm volatile(
                "global_load_dwordx4 %0, %8, off sc0 sc1\n\t"
                "global_load_dwordx4 %1, %8, off offset:16 sc0 sc1\n\t"
                "global_load_dwordx4 %2, %8, off offset:32 sc0 sc1\n\t"
                "global_load_dwordx4 %3, %8, off offset:48 sc0 sc1\n\t"
                "global_load_dwordx4 %4, %8, off offset:64 sc0 sc1\n\t"
                "global_load_dwordx4 %5, %8, off offset:80 sc0 sc1\n\t"
                "global_load_dwordx4 %6, %8, off offset:96 sc0 sc1\n\t"
                "global_load_dwordx4 %7, %8, off offset:112 sc0 sc1\n\t"
                "s_waitcnt vmcnt(0)"
                : "=&v"(v0), "=&v"(v1), "=&v"(v2), "=&v"(v3),
                  "=&v"(v4), "=&v"(v5), "=&v"(v6), "=&v"(v7)
                : "v"(src)
                : "memory");
            int r0   = 2 * tid;
            int off0 = (r0 >> 6) * CHUNKW + (r0 & 63) * ROWW;   // r0 even -> r0+1 same chunk
            *(float4*)&hlds[off0 + 0]         = v0;
            *(float4*)&hlds[off0 + 4]         = v1;
            *(float4*)&hlds[off0 + 8]         = v2;
            *(float4*)&hlds[off0 + 12]        = v3;
            *(float4*)&hlds[off0 + ROWW + 0]  = v4;
            *(float4*)&hlds[off0 + ROWW + 4]  = v5;
            *(float4*)&hlds[off0 + ROWW + 8]  = v6;
            *(float4*)&hlds[off0 + ROWW + 12] = v7;
        }
        __syncthreads();

        // ---- partial dots: 2 gates x 16 b x 64 k per thread, from LDS ----
        float accA[GB], accB[GB];
        #pragma unroll
        for (int b = 0; b < GB; ++b) { accA[b] = 0.f; accB[b] = 0.f; }

        const int cbase = kq * CHUNKW;
        #pragma unroll
        for (int kk = 0; kk < 64; ++kk) {
            const float* hr = &hlds[cbase + kk * ROWW];
            float h[GB];
            *(float4*)(h + 0)  = *(const float4*)(hr + 0);
            *(float4*)(h + 4)  = *(const float4*)(hr + 4);
            *(float4*)(h + 8)  = *(const float4*)(hr + 8);
            *(float4*)(h + 12) = *(const float4*)(hr + 12);
            float wa = wA[kk], wb = wB[kk];
            #pragma unroll
            for (int b = 0; b < GB; ++b) {
                accA[b] = fmaf(h[b], wa, accA[b]);
                accB[b] = fmaf(h[b], wb, accB[b]);
            }
        }

        // ---- reduce across 8 kq lanes ----
        #pragma unroll
        for (int m = 1; m < 8; m <<= 1) {
            #pragma unroll
            for (int b = 0; b < GB; ++b) {
                accA[b] += __shfl_xor(accA[b], m, 64);
                accB[b] += __shfl_xor(accB[b], m, 64);
            }
        }
        if (kq == 0) {
            #pragma unroll
            for (int b = 0; b < GB; ++b) {
                part[(n * 4 + g2 * 2 + 0) * GB + b] = accA[b];
                part[(n * 4 + g2 * 2 + 1) * GB + b] = accB[b];
            }
        }
        __syncthreads();

        // ---- epilogue: one (n,b) per thread ----
        float aI = fmaf(xv, w0I, biasI) + part[(ne * 4 + 0) * GB + be];
        float aF = fmaf(xv, w0F, biasF) + part[(ne * 4 + 1) * GB + be];
        float aC = fmaf(xv, w0C, biasC) + part[(ne * 4 + 2) * GB + be];
        float aO = fmaf(xv, w0O, biasO) + part[(ne * 4 + 3) * GB + be];
        float I  = 1.0f / (1.0f + expf(-aI));
        float F  = 1.0f / (1.0f + expf(-aF));
        float Ch = tanhf(aC);
        Cst = fmaf(F, Cst, I * Ch);
        float Hn = aO * tanhf(Cst);        // reference: O has NO sigmoid

        if (t < SEQ - 1) {
            // block's 256 outputs form a contiguous 1 KB region -> coalesced sc1 stores
            float* dst = hbuf + ((t + 1) & 1) * HT + g * GSTRIDE + neg * GB + be;
            __hip_atomic_store(dst, Hn, __ATOMIC_RELAXED, __HIP_MEMORY_SCOPE_AGENT);
            __syncthreads();               // compiler drains vmcnt(0) before s_barrier
            if (tid == 0) {
                __hip_atomic_store(myflag, t + 1, __ATOMIC_RELAXED, __HIP_MEMORY_SCOPE_AGENT);
            }
        } else {
            int o = bg * HID + neg;
            out[o] = Hn; out[BATCH * HID + o] = Hn; out[2 * BATCH * HID + o] = Cst;
        }
    }
}

extern "C" void kernel_launch(void* const* d_in, const int* in_sizes, int n_in,
                              void* d_out, int out_size, void* d_ws, size_t ws_size,
                              hipStream_t stream) {
    const float* x  = (const float*)d_in[0];
    const float* H0 = (const float*)d_in[1];
    const float* C0 = (const float*)d_in[2];
    const float* Wi = (const float*)d_in[3];
    const float* bi = (const float*)d_in[4];
    const float* Wf = (const float*)d_in[5];
    const float* bf = (const float*)d_in[6];
    const float* Wc = (const float*)d_in[7];
    const float* bc = (const float*)d_in[8];
    const float* Wo = (const float*)d_in[9];
    const float* bo = (const float*)d_in[10];
    float* out = (float*)d_out;
    float* ws  = (float*)d_ws;   // 2*256KB H + 2KB flags

    const int init_elems = HT + NGROUP * 64;
    hipLaunchKernelGGL(lstm_init, dim3((init_elems + 255) / 256), dim3(256), 0, stream,
                       H0, ws);
    hipLaunchKernelGGL(lstm_main, dim3(NGROUP * BPG), dim3(256), 0, stream,
                       x, C0, Wi, bi, Wf, bf, Wc, bc, Wo, bo, out, ws);
}

// Round 6
// 1389.187 us; speedup vs baseline: 23.8557x; 5.2329x over previous
//
#include <hip/hip_runtime.h>
#include <math.h>

#define SEQ 512
#define HID 512
#define NGROUP 8              // batch groups of 16; group g = bid & 7
#define GB 16                 // batches per group
#define BPG 32                // blocks per group (each owns 16 n-cols)
#define SLOTU 65536           // ushorts per H slot ([g][b16][k512] bf16)
#define GSLOTU 8192           // ushorts per group per slot (16 KB)
#define LROW 520              // LDS row stride in ushorts (512 + 8 pad -> balanced banks)
// ws layout: [0, 256 KB) two bf16 H slots | [256 KB, +2 KB) flags (8 groups * 64 ints)

typedef __attribute__((ext_vector_type(8))) short short8;   // 8 bf16 = 4 VGPRs (MFMA A/B)
typedef __attribute__((ext_vector_type(4))) float floatx4;  // MFMA C/D

__device__ __forceinline__ unsigned short f2bf(float f) {   // RNE fp32->bf16
    unsigned u = __builtin_bit_cast(unsigned, f);
    return (unsigned short)((u + 0x7FFFu + ((u >> 16) & 1u)) >> 16);
}
__device__ __forceinline__ float bf2f(unsigned short h) {
    unsigned u = ((unsigned)h) << 16;
    return __builtin_bit_cast(float, u);
}
__device__ __forceinline__ float fast_sigmoid(float x) {
    return 1.0f / (1.0f + __expf(-x));
}
__device__ __forceinline__ float fast_tanh(float x) {       // stable for |x| large
    float e = __expf(-2.0f * fabsf(x));
    float t = (1.0f - e) / (1.0f + e);
    return x < 0.0f ? -t : t;
}

__global__ void lstm_init(const float* __restrict__ H0, unsigned short* __restrict__ hb) {
    int idx = blockIdx.x * blockDim.x + threadIdx.x;
    if (idx < SLOTU) {
        int k = idx & 511, b = (idx >> 9) & 15, g = idx >> 13;
        hb[idx] = f2bf(H0[(g * GB + b) * HID + k]);       // slot0 = H(t=0)
    } else if (idx < SLOTU + NGROUP * 64) {
        ((int*)(hb + 2 * SLOTU))[idx - SLOTU] = 0;        // flags = 0
    }
}

__global__ __launch_bounds__(256, 1)
void lstm_main(const float* __restrict__ x,
               const float* __restrict__ C0,
               const float* __restrict__ Wi, const float* __restrict__ bi,
               const float* __restrict__ Wf, const float* __restrict__ bf_,
               const float* __restrict__ Wc, const float* __restrict__ bc,
               const float* __restrict__ Wo, const float* __restrict__ bo,
               float* __restrict__ out, unsigned short* __restrict__ hb) {
    int* flags = (int*)(hb + 2 * SLOTU);

    const int bid  = blockIdx.x;
    const int g    = bid & 7;
    const int cb   = bid >> 3;
    const int tid  = threadIdx.x;
    const int w    = tid >> 6;          // wave 0..3 (owns cols cb*16+w*4 .. +3)
    const int lane = tid & 63;
    const int q    = lane >> 4;         // quad
    const int c    = lane & 15;         // low lane bits

    // MFMA index roles (m89/m91/m120-verified layouts):
    //   A-frag: lane holds A[m = lane&15][k = quad*8+j]   (m = col_local*4 + gate)
    //   B-frag: lane holds B[k = quad*8+j][n = lane&15]   (n = batch)
    //   D:      lane holds D[m = quad*4+r][n = lane&15]   (r = gate, col_local = quad)
    const int gate = c & 3;                       // for A-frag build
    const int colA = cb * 16 + w * 4 + (c >> 2);  // A-frag column
    const int colD = cb * 16 + w * 4 + q;         // this lane's output column
    const int bD   = g * GB + c;                  // this lane's batch

    // ---- A-fragments: hi+lo bf16 split of W, step-invariant, in registers ----
    const float* Wg = (gate == 0) ? Wi : (gate == 1) ? Wf : (gate == 2) ? Wc : Wo;
    short8 aHi[16], aLo[16];
    #pragma unroll
    for (int kt = 0; kt < 16; ++kt) {
        #pragma unroll
        for (int j = 0; j < 8; ++j) {
            int k = kt * 32 + q * 8 + j;
            float wv = Wg[(k + 1) * HID + colA];   // rows 1..512 are H weights
            unsigned short hi = f2bf(wv);
            unsigned short lo = f2bf(wv - bf2f(hi));
            aHi[kt][j] = (short)hi;
            aLo[kt][j] = (short)lo;
        }
    }

    // epilogue constants (row 0 = x weight, bias) + C state, all for (colD, bD)
    const float biasI = bi[colD], biasF = bf_[colD], biasC = bc[colD], biasO = bo[colD];
    const float w0I = Wi[colD], w0F = Wf[colD], w0C = Wc[colD], w0O = Wo[colD];
    float Cst = C0[bD * HID + colD];
    const float* xrow = x + bD * SEQ;

    __shared__ unsigned short hlds[16 * LROW];   // 16.6 KB staged H tile [b][k] bf16

    int* myflag = flags + g * 64 + cb;

    for (int t = 0; t < SEQ; ++t) {
        // ---- wait for all 32 producer flags of this group (throttled poll) ----
        if (tid < BPG) {
            const int* fp = flags + g * 64 + tid;
            while (__hip_atomic_load(fp, __ATOMIC_RELAXED, __HIP_MEMORY_SCOPE_AGENT) < t)
                __builtin_amdgcn_s_sleep(2);
        }
        __syncthreads();

        // ---- stage 16 KB H_t tile: 64 B/thread, coherent dwordx4 burst ----
        {
            const unsigned short* gsrc = hb + (t & 1) * SLOTU + g * GSLOTU + tid * 32;
            float4 v0, v1, v2, v3;
            asm volatile(
                "global_load_dwordx4 %0, %4, off sc0 sc1\n\t"
                "global_load_dwordx4 %1, %4, off offset:16 sc0 sc1\n\t"
                "global_load_dwordx4 %2, %4, off offset:32 sc0 sc1\n\t"
                "global_load_dwordx4 %3, %4, off offset:48 sc0 sc1\n\t"
                "s_waitcnt vmcnt(0)"
                : "=&v"(v0), "=&v"(v1), "=&v"(v2), "=&v"(v3)
                : "v"(gsrc) : "memory");
            int b = tid >> 4, ch = tid & 15;
            unsigned short* dst = hlds + b * LROW + ch * 32;
            *(float4*)(dst + 0)  = v0;
            *(float4*)(dst + 8)  = v1;
            *(float4*)(dst + 16) = v2;
            *(float4*)(dst + 24) = v3;
        }
        __syncthreads();

        // ---- GEMM: D[64x16] = W^T (hi+lo) x H, 16 K-tiles, A in regs, B from LDS ----
        floatx4 acc = {0.f, 0.f, 0.f, 0.f};
        const unsigned short* brow = hlds + c * LROW + q * 8;
        #pragma unroll
        for (int kt = 0; kt < 16; ++kt) {
            short8 bfrag = *(const short8*)(brow + kt * 32);
            acc = __builtin_amdgcn_mfma_f32_16x16x32_bf16(aHi[kt], bfrag, acc, 0, 0, 0);
            acc = __builtin_amdgcn_mfma_f32_16x16x32_bf16(aLo[kt], bfrag, acc, 0, 0, 0);
        }

        // ---- in-lane epilogue: acc[r] = gate r pre-activation (H part) ----
        float xv  = xrow[t];
        float aIv = acc[0] + fmaf(xv, w0I, biasI);
        float aFv = acc[1] + fmaf(xv, w0F, biasF);
        float aCv = acc[2] + fmaf(xv, w0C, biasC);
        float aOv = acc[3] + fmaf(xv, w0O, biasO);
        float I  = fast_sigmoid(aIv);
        float F  = fast_sigmoid(aFv);
        float Ch = fast_tanh(aCv);
        Cst = fmaf(F, Cst, I * Ch);
        float Hn = aOv * fast_tanh(Cst);      // reference: O has NO sigmoid

        if (t < SEQ - 1) {
            // pack neighbor cols (q, q+1) into one 4-B coherent store
            int v = (int)f2bf(Hn);
            int o = __shfl_xor(v, 16);        // partner quad's bf16
            if ((q & 1) == 0) {
                unsigned val = (unsigned)(unsigned short)v |
                               ((unsigned)(unsigned short)o << 16);
                unsigned* dst = (unsigned*)(hb + ((t + 1) & 1) * SLOTU + g * GSLOTU
                                            + c * 512 + colD);   // colD even here
                __hip_atomic_store(dst, val, __ATOMIC_RELAXED, __HIP_MEMORY_SCOPE_AGENT);
            }
            __syncthreads();                  // barrier drains vmcnt(0) (tracked stores)
            if (tid == 0)
                __hip_atomic_store(myflag, t + 1, __ATOMIC_RELAXED, __HIP_MEMORY_SCOPE_AGENT);
        } else {
            int o = bD * HID + colD;
            out[o] = Hn; out[65536 + o] = Hn; out[131072 + o] = Cst;
        }
    }
}

extern "C" void kernel_launch(void* const* d_in, const int* in_sizes, int n_in,
                              void* d_out, int out_size, void* d_ws, size_t ws_size,
                              hipStream_t stream) {
    const float* x  = (const float*)d_in[0];
    const float* H0 = (const float*)d_in[1];
    const float* C0 = (const float*)d_in[2];
    const float* Wi = (const float*)d_in[3];
    const float* bi = (const float*)d_in[4];
    const float* Wf = (const float*)d_in[5];
    const float* bf = (const float*)d_in[6];
    const float* Wc = (const float*)d_in[7];
    const float* bc = (const float*)d_in[8];
    const float* Wo = (const float*)d_in[9];
    const float* bo = (const float*)d_in[10];
    float* out = (float*)d_out;
    unsigned short* hb = (unsigned short*)d_ws;   // 256 KB H slots + 2 KB flags

    const int init_elems = SLOTU + NGROUP * 64;
    hipLaunchKernelGGL(lstm_init, dim3((init_elems + 255) / 256), dim3(256), 0, stream,
                       H0, hb);
    hipLaunchKernelGGL(lstm_main, dim3(NGROUP * BPG), dim3(256), 0, stream,
                       x, C0, Wi, bi, Wf, bf, Wc, bc, Wo, bo, out, hb);
}